// Round 20
// baseline (786.477 us; speedup 1.0000x reference)
//
#include <hip/hip_runtime.h>
#include <stdint.h>

#define N_ROWS 100000
#define D_IN 512
#define H_DIM 2048
#define HEADS 4
#define NSEG 10000

typedef unsigned short u16;
typedef __attribute__((ext_vector_type(4))) float f32x4;
typedef __attribute__((ext_vector_type(16))) float f32x16;
typedef __attribute__((ext_vector_type(8))) __bf16 bf16x8;
typedef __attribute__((ext_vector_type(8))) u16 u16x8;
typedef __attribute__((ext_vector_type(4))) u16 u16x4;

__device__ __forceinline__ u16 f2bf(float f) {
  union { float f; uint32_t u; } v; v.f = f;
  uint32_t r = (v.u + 0x7FFF + ((v.u >> 16) & 1)) >> 16;
  return (u16)r;
}

// ---------------- init: bias1, zero segsum ---------------------------------
__global__ void init_misc(const float* __restrict__ W1, const float* __restrict__ b1,
                          const float* __restrict__ alpha, float* __restrict__ bias1,
                          float* __restrict__ segsum) {
  int i = blockIdx.x * 256 + threadIdx.x;
  if (i < NSEG * HEADS) segsum[i] = 0.f;
  if (i < H_DIM) bias1[i] = b1[i] + alpha[0] * W1[(size_t)D_IN * H_DIM + i];
}

// ---------------- prep: gwa4[d] = ln_g[d]*Wa[d][0..3]; S1,S2 consts --------
__global__ __launch_bounds__(512) void prep_gwa(const float* __restrict__ ln_g,
                                                const float* __restrict__ ln_b,
                                                const float* __restrict__ Wa,
                                                f32x4* __restrict__ gwa4,
                                                float* __restrict__ consts) {
  int d = threadIdx.x;
  if (d < 8) consts[d] = 0.f;
  __syncthreads();
  float gg = ln_g[d], bb = ln_b[d];
  f32x4 wa = *(const f32x4*)(Wa + (size_t)d * 4);
  f32x4 gw;
  gw[0] = gg * wa[0]; gw[1] = gg * wa[1]; gw[2] = gg * wa[2]; gw[3] = gg * wa[3];
  gwa4[d] = gw;
  atomicAdd(&consts[0], gw[0]); atomicAdd(&consts[1], gw[1]);
  atomicAdd(&consts[2], gw[2]); atomicAdd(&consts[3], gw[3]);
  atomicAdd(&consts[4], bb * wa[0]); atomicAdd(&consts[5], bb * wa[1]);
  atomicAdd(&consts[6], bb * wa[2]); atomicAdd(&consts[7], bb * wa[3]);
}

// ---------------- cast x (fp32) -> xb (bf16) -------------------------------
__global__ void cast_x_kernel(const float* __restrict__ x, u16* __restrict__ xb, long n4) {
  long i = (long)blockIdx.x * 256 + threadIdx.x;
  if (i >= n4) return;
  f32x4 v = *(const f32x4*)(x + i * 4);
  u16x4 o;
  o[0] = f2bf(v[0]); o[1] = f2bf(v[1]); o[2] = f2bf(v[2]); o[3] = f2bf(v[3]);
  *(u16x4*)(xb + i * 4) = o;
}

// ---------------- transpose + cast: in[R][C] fp32 -> out[C][R] bf16 --------
__global__ __launch_bounds__(256) void transpose_cast(const float* __restrict__ in,
                                                      u16* __restrict__ outT,
                                                      int R, int Cc) {
  __shared__ float t[32][33];
  const int c0 = blockIdx.x * 32, r0 = blockIdx.y * 32;
  const int tx = threadIdx.x, ty = threadIdx.y;  // 32 x 8
#pragma unroll
  for (int i = 0; i < 4; ++i)
    t[ty + 8 * i][tx] = in[(size_t)(r0 + ty + 8 * i) * Cc + c0 + tx];
  __syncthreads();
#pragma unroll
  for (int i = 0; i < 4; ++i) {
    int oc = ty + 8 * i;
    outT[(size_t)(c0 + oc) * R + r0 + tx] = f2bf(t[tx][oc]);
  }
}

// ============================================================================
// GEMM1 — r19 skeleton with 32x32x16 MFMA (A/B use identical lane->k
// convention so internal k-permutation cancels; C/D mapping HW-verified:
// col=lane&31, row=(reg&3)+8*(reg>>2)+4*(lane>>5)). 16 MFMA + 16 ds_read
// per K-tile (vs 32+24 at 16x16): half the matrix-pipe issue slots, 15%
// faster per-FLOP pipe. Staging/sync/swizzle byte-identical to r19.
// ============================================================================
template <int RELU>
__global__ __launch_bounds__(256, 3) void gemm128x(const u16* __restrict__ A,
                                                   const u16* __restrict__ Bt,
                                                   const float* __restrict__ bias,
                                                   u16* __restrict__ C,
                                                   int M, int Nc, int K, int NTN) {
  __shared__ __align__(16) char smem[32768];
  const int tid = threadIdx.x;
  const int w = tid >> 6, l = tid & 63;
  const int wm = w >> 1, wn = w & 1;  // 2 x 2 waves, 64x64 out each
  const int l31 = l & 31, hi = l >> 5;

  // T1: bijective XCD swizzle (m204)
  const int nwg = gridDim.x;
  const int orig = blockIdx.x;
  const int qq = nwg >> 3, rr = nwg & 7, xcd = orig & 7, idx = orig >> 3;
  const int wgid = (xcd < rr ? xcd * (qq + 1) : rr * (qq + 1) + (xcd - rr) * qq) + idx;
  const int rowBase = (wgid / NTN) * 128;
  const int colBase = (wgid % NTN) * 128;

  const int NT = K >> 6;  // BK = 64

  // staging source pre-swizzle (identical to r19): LDS byte q holds global
  // elem o = q ^ (((q>>7)&7)<<4)
  int s_row[4], s_kel[4];
#pragma unroll
  for (int p = 0; p < 4; ++p) {
    int q = p * 4096 + w * 1024 + l * 16;
    int o = q ^ (((q >> 7) & 7) << 4);
    s_row[p] = o >> 7;
    s_kel[p] = (o & 127) >> 1;
  }

  f32x16 acc[2][2] = {};

  const int aRowB = (wm * 64 + l31) * 128;  // byte base of lane's A row (m=0)
  const int bRowB = (wn * 64 + l31) * 128;
  const int rx = l31 & 7;  // row&7 (same for m=0/1: +32 keeps low 3 bits)

  for (int t = 0; t < NT; ++t) {
    __syncthreads();  // WAR
#pragma unroll
    for (int p = 0; p < 4; ++p) {
      int r = rowBase + s_row[p];
      if (r >= M) r = M - 1;
      const u16* asrc = A + (size_t)r * K + t * 64 + s_kel[p];
      __builtin_amdgcn_global_load_lds(
          (const __attribute__((address_space(1))) void*)asrc,
          (__attribute__((address_space(3))) void*)(smem + p * 4096 + w * 1024), 16, 0, 0);
    }
#pragma unroll
    for (int p = 0; p < 4; ++p) {
      int rc = colBase + s_row[p];
      const u16* bsrc = Bt + (size_t)rc * K + t * 64 + s_kel[p];
      __builtin_amdgcn_global_load_lds(
          (const __attribute__((address_space(1))) void*)bsrc,
          (__attribute__((address_space(3))) void*)(smem + 16384 + p * 4096 + w * 1024), 16, 0, 0);
    }
    __syncthreads();  // publish

#pragma unroll
    for (int k2 = 0; k2 < 4; ++k2) {  // 4 x K=16
      const int cs = ((k2 * 2 + hi) ^ rx) << 4;  // global chunk k2*2+hi, swizzled
      bf16x8 a0 = *(const bf16x8*)(smem + aRowB + cs);
      bf16x8 a1 = *(const bf16x8*)(smem + aRowB + 4096 + cs);  // +32 rows
      bf16x8 b0 = *(const bf16x8*)(smem + 16384 + bRowB + cs);
      bf16x8 b1 = *(const bf16x8*)(smem + 16384 + bRowB + 4096 + cs);
      __builtin_amdgcn_s_setprio(1);
      acc[0][0] = __builtin_amdgcn_mfma_f32_32x32x16_bf16(a0, b0, acc[0][0], 0, 0, 0);
      acc[0][1] = __builtin_amdgcn_mfma_f32_32x32x16_bf16(a0, b1, acc[0][1], 0, 0, 0);
      acc[1][0] = __builtin_amdgcn_mfma_f32_32x32x16_bf16(a1, b0, acc[1][0], 0, 0, 0);
      acc[1][1] = __builtin_amdgcn_mfma_f32_32x32x16_bf16(a1, b1, acc[1][1], 0, 0, 0);
      __builtin_amdgcn_s_setprio(0);
    }
  }

  // epilogue: bias + relu, bf16 store. C/D map: col=l31, row=(reg&3)+8*(reg>>2)+4*hi
#pragma unroll
  for (int n = 0; n < 2; ++n) {
    int col = colBase + wn * 64 + n * 32 + l31;
    float bb = bias[col];
#pragma unroll
    for (int m = 0; m < 2; ++m) {
#pragma unroll
      for (int reg = 0; reg < 16; ++reg) {
        int row = rowBase + wm * 64 + m * 32 + (reg & 3) + 8 * (reg >> 2) + 4 * hi;
        if (row < M) {
          float v = acc[m][n][reg] + bb;
          if (RELU) v = fmaxf(v, 0.f);
          C[(size_t)row * Nc + col] = f2bf(v);
        }
      }
    }
  }
}

// ============================================================================
// GEMM2 — r19 verbatim (16x16 MFMA + FUSE_LN plain-store partial reduction).
// ============================================================================
template <int RELU, int FUSE_LN>
__global__ __launch_bounds__(256, 3) void gemm128h(const u16* __restrict__ A,
                                                   const u16* __restrict__ Bt,
                                                   const float* __restrict__ bias,
                                                   u16* __restrict__ C,
                                                   const f32x4* __restrict__ gwa4,
                                                   float* __restrict__ red,
                                                   size_t ctStride,
                                                   int M, int Nc, int K, int NTN) {
  __shared__ __align__(16) char smem[32768];
  const int tid = threadIdx.x;
  const int w = tid >> 6, l = tid & 63;
  const int wm = w >> 1, wn = w & 1;
  const int lr = l & 15, g = l >> 4;

  const int nwg = gridDim.x;
  const int orig = blockIdx.x;
  const int qq = nwg >> 3, rr = nwg & 7, xcd = orig & 7, idx = orig >> 3;
  const int wgid = (xcd < rr ? xcd * (qq + 1) : rr * (qq + 1) + (xcd - rr) * qq) + idx;
  const int rowBase = (wgid / NTN) * 128;
  const int ct = wgid % NTN;
  const int colBase = ct * 128;

  const int NT = K >> 6;

  int s_row[4], s_kel[4];
#pragma unroll
  for (int p = 0; p < 4; ++p) {
    int q = p * 4096 + w * 1024 + l * 16;
    int o = q ^ (((q >> 7) & 7) << 4);
    s_row[p] = o >> 7;
    s_kel[p] = (o & 127) >> 1;
  }

  f32x4 acc[4][4] = {};

  const int aRow = (wm * 64 + lr) * 128;
  const int bRow = (wn * 64 + lr) * 128;
  int ck[2];
  ck[0] = (g ^ (lr & 7)) << 4;
  ck[1] = ((4 + g) ^ (lr & 7)) << 4;

  for (int t = 0; t < NT; ++t) {
    __syncthreads();
#pragma unroll
    for (int p = 0; p < 4; ++p) {
      int r = rowBase + s_row[p];
      if (r >= M) r = M - 1;
      const u16* asrc = A + (size_t)r * K + t * 64 + s_kel[p];
      __builtin_amdgcn_global_load_lds(
          (const __attribute__((address_space(1))) void*)asrc,
          (__attribute__((address_space(3))) void*)(smem + p * 4096 + w * 1024), 16, 0, 0);
    }
#pragma unroll
    for (int p = 0; p < 4; ++p) {
      int rc = colBase + s_row[p];
      const u16* bsrc = Bt + (size_t)rc * K + t * 64 + s_kel[p];
      __builtin_amdgcn_global_load_lds(
          (const __attribute__((address_space(1))) void*)bsrc,
          (__attribute__((address_space(3))) void*)(smem + 16384 + p * 4096 + w * 1024), 16, 0, 0);
    }
    __syncthreads();

#pragma unroll
    for (int kk = 0; kk < 2; ++kk) {
      bf16x8 af[4], bf[4];
#pragma unroll
      for (int mi = 0; mi < 4; ++mi)
        af[mi] = *(const bf16x8*)(smem + aRow + mi * 2048 + ck[kk]);
#pragma unroll
      for (int ni = 0; ni < 4; ++ni)
        bf[ni] = *(const bf16x8*)(smem + 16384 + bRow + ni * 2048 + ck[kk]);
      __builtin_amdgcn_s_setprio(1);
#pragma unroll
      for (int mi = 0; mi < 4; ++mi)
#pragma unroll
        for (int ni = 0; ni < 4; ++ni)
          acc[mi][ni] = __builtin_amdgcn_mfma_f32_16x16x32_bf16(af[mi], bf[ni], acc[mi][ni], 0, 0, 0);
      __builtin_amdgcn_s_setprio(0);
    }
  }

  if (FUSE_LN) {
    float* redc = red + (size_t)ct * ctStride;
#pragma unroll
    for (int mi = 0; mi < 4; ++mi) {
      float dt[4][4], sv[4], sq[4];
#pragma unroll
      for (int r = 0; r < 4; ++r) {
        sv[r] = 0.f; sq[r] = 0.f;
#pragma unroll
        for (int h = 0; h < 4; ++h) dt[r][h] = 0.f;
      }
#pragma unroll
      for (int ni = 0; ni < 4; ++ni) {
        int col = colBase + wn * 64 + ni * 16 + lr;
        f32x4 gw = gwa4[col];
        float bb = bias[col];
#pragma unroll
        for (int r = 0; r < 4; ++r) {
          float v = acc[mi][ni][r] + bb;
          if (RELU) v = fmaxf(v, 0.f);
          sv[r] += v; sq[r] += v * v;
          dt[r][0] += v * gw[0]; dt[r][1] += v * gw[1];
          dt[r][2] += v * gw[2]; dt[r][3] += v * gw[3];
        }
      }
#pragma unroll
      for (int off = 1; off < 16; off <<= 1) {
#pragma unroll
        for (int r = 0; r < 4; ++r) {
          sv[r] += __shfl_xor(sv[r], off);
          sq[r] += __shfl_xor(sq[r], off);
#pragma unroll
          for (int h = 0; h < 4; ++h) dt[r][h] += __shfl_xor(dt[r][h], off);
        }
      }
      if (lr == 0) {
#pragma unroll
        for (int r = 0; r < 4; ++r) {
          int row = rowBase + wm * 64 + mi * 16 + g * 4 + r;
          if (row < M) {
            float* rp = redc + ((size_t)row * 2 + wn) * 6;
            rp[0] = dt[r][0]; rp[1] = dt[r][1]; rp[2] = dt[r][2];
            rp[3] = dt[r][3]; rp[4] = sv[r];    rp[5] = sq[r];
          }
        }
      }
    }
  } else {
    float bv[4];
#pragma unroll
    for (int ni = 0; ni < 4; ++ni) bv[ni] = bias[colBase + wn * 64 + ni * 16 + lr];
#pragma unroll
    for (int mi = 0; mi < 4; ++mi) {
#pragma unroll
      for (int r = 0; r < 4; ++r) {
        int row = rowBase + wm * 64 + mi * 16 + g * 4 + r;
        if (row < M) {
#pragma unroll
          for (int ni = 0; ni < 4; ++ni) {
            float v = acc[mi][ni][r] + bv[ni];
            if (RELU) v = fmaxf(v, 0.f);
            C[(size_t)row * Nc + colBase + wn * 64 + ni * 16 + lr] = f2bf(v);
          }
        }
      }
    }
  }
}

// ---------------- finalize LN + att + sigmoid + exp + seg-sum --------------
__global__ void ln_final(const float* __restrict__ red, size_t ctStride,
                         const float* __restrict__ consts,
                         const float* __restrict__ ba, const int* __restrict__ row,
                         float* __restrict__ att, float* __restrict__ segsum) {
  int n = blockIdx.x * 256 + threadIdx.x;
  if (n >= N_ROWS) return;
  float acc6[6] = {0.f, 0.f, 0.f, 0.f, 0.f, 0.f};
#pragma unroll
  for (int ct = 0; ct < 4; ++ct) {
#pragma unroll
    for (int hw = 0; hw < 2; ++hw) {
      const float* rp = red + (size_t)ct * ctStride + ((size_t)n * 2 + hw) * 6;
#pragma unroll
      for (int k = 0; k < 6; ++k) acc6[k] += rp[k];
    }
  }
  float mu = acc6[4] * (1.f / 512.f);
  float var = acc6[5] * (1.f / 512.f) - mu * mu;
  float rstd = rsqrtf(var + 1e-5f);
  int rid = row[n];
#pragma unroll
  for (int h = 0; h < 4; ++h) {
    float raw = rstd * (acc6[h] - mu * consts[h]) + consts[4 + h] + ba[h];
    float sg = 1.f / (1.f + expf(-raw));
    float e = expf(sg);
    att[(size_t)n * 4 + h] = e;
    atomicAdd(&segsum[(size_t)rid * 4 + h], e);
  }
}

// ---------------- normalize + head-mean ------------------------------------
__global__ void seg_norm(const float* __restrict__ att, const int* __restrict__ row,
                         const float* __restrict__ segsum, float* __restrict__ out) {
  int n = blockIdx.x * 256 + threadIdx.x;
  if (n >= N_ROWS) return;
  int rid = row[n];
  float s = 0.f;
#pragma unroll
  for (int h = 0; h < 4; ++h)
    s += att[(size_t)n * 4 + h] / segsum[(size_t)rid * 4 + h];
  out[n] = 0.25f * s;
}

extern "C" void kernel_launch(void* const* d_in, const int* in_sizes, int n_in,
                              void* d_out, int out_size, void* d_ws, size_t ws_size,
                              hipStream_t stream) {
  const float* x = (const float*)d_in[0];
  const int* row = (const int*)d_in[1];
  const float* alpha = (const float*)d_in[2];
  const float* W1 = (const float*)d_in[3];
  const float* b1 = (const float*)d_in[4];
  const float* W2 = (const float*)d_in[5];
  const float* b2 = (const float*)d_in[6];
  const float* ln_g = (const float*)d_in[7];
  const float* ln_b = (const float*)d_in[8];
  const float* Wa = (const float*)d_in[9];
  const float* ba = (const float*)d_in[10];
  float* out = (float*)d_out;

  char* ws = (char*)d_ws;
  size_t off = 0;
  auto alloc = [&](size_t bytes) {
    void* p = ws + off;
    off += (bytes + 255) & ~(size_t)255;
    return p;
  };
  u16* W1t = (u16*)alloc((size_t)H_DIM * D_IN * 2);
  u16* W2t = (u16*)alloc((size_t)D_IN * H_DIM * 2);
  float* bias1 = (float*)alloc(H_DIM * 4);
  float* att = (float*)alloc((size_t)N_ROWS * HEADS * 4);
  float* segsum = (float*)alloc(NSEG * HEADS * 4);
  f32x4* gwa4 = (f32x4*)alloc(D_IN * 16);
  float* consts = (float*)alloc(8 * 4);
  const size_t ctStride = (size_t)N_ROWS * 2 * 6;
  float* red = (float*)alloc(4 * ctStride * 4);

  const size_t per_row = ((size_t)D_IN + H_DIM) * 2;
  const size_t reserve = (size_t)1 << 20;
  size_t usable = (ws_size > off + reserve) ? (ws_size - off - reserve) : 0;
  long slab_l = (long)(usable / per_row);
  const int maxslab = (N_ROWS + 127) & ~127;
  int slab;
  if (slab_l >= maxslab) slab = maxslab;
  else slab = (int)(slab_l & ~127L);
  if (slab < 128) slab = 128;

  u16* xb = (u16*)alloc((size_t)slab * D_IN * 2);
  u16* h1 = (u16*)alloc((size_t)slab * H_DIM * 2);

  init_misc<<<(NSEG * HEADS + 255) / 256, 256, 0, stream>>>(W1, b1, alpha, bias1, segsum);
  prep_gwa<<<1, 512, 0, stream>>>(ln_g, ln_b, Wa, gwa4, consts);
  transpose_cast<<<dim3(H_DIM / 32, D_IN / 32), dim3(32, 8), 0, stream>>>(W1, W1t, D_IN, H_DIM);
  transpose_cast<<<dim3(D_IN / 32, H_DIM / 32), dim3(32, 8), 0, stream>>>(W2, W2t, H_DIM, D_IN);

  for (int s0 = 0; s0 < N_ROWS; s0 += slab) {
    int rows = N_ROWS - s0 < slab ? N_ROWS - s0 : slab;
    int ntm = (rows + 127) / 128;
    long n4 = (long)rows * D_IN / 4;
    cast_x_kernel<<<(int)((n4 + 255) / 256), 256, 0, stream>>>(x + (size_t)s0 * D_IN, xb, n4);
    gemm128x<1><<<ntm * (H_DIM / 128), 256, 0, stream>>>(
        xb, W1t, bias1, h1, rows, H_DIM, D_IN, H_DIM / 128);
    gemm128h<1, 1><<<ntm * (D_IN / 128), 256, 0, stream>>>(
        h1, W2t, b2, nullptr, gwa4, red + (size_t)s0 * 2 * 6, ctStride,
        rows, D_IN, H_DIM, D_IN / 128);
  }

  ln_final<<<(N_ROWS + 255) / 256, 256, 0, stream>>>(red, ctStride, consts, ba, row, att, segsum);
  seg_norm<<<(N_ROWS + 255) / 256, 256, 0, stream>>>(att, row, segsum, out);
}

// Round 21
// 657.862 us; speedup vs baseline: 1.1955x; 1.1955x over previous
//
#include <hip/hip_runtime.h>
#include <stdint.h>

#define N_ROWS 100000
#define D_IN 512
#define H_DIM 2048
#define HEADS 4
#define NSEG 10000

typedef unsigned short u16;
typedef __attribute__((ext_vector_type(4))) float f32x4;
typedef __attribute__((ext_vector_type(8))) __bf16 bf16x8;
typedef __attribute__((ext_vector_type(8))) u16 u16x8;
typedef __attribute__((ext_vector_type(4))) u16 u16x4;

__device__ __forceinline__ u16 f2bf(float f) {
  union { float f; uint32_t u; } v; v.f = f;
  uint32_t r = (v.u + 0x7FFF + ((v.u >> 16) & 1)) >> 16;
  return (u16)r;
}

// ---------------- init: bias1, zero segsum ---------------------------------
__global__ void init_misc(const float* __restrict__ W1, const float* __restrict__ b1,
                          const float* __restrict__ alpha, float* __restrict__ bias1,
                          float* __restrict__ segsum) {
  int i = blockIdx.x * 256 + threadIdx.x;
  if (i < NSEG * HEADS) segsum[i] = 0.f;
  if (i < H_DIM) bias1[i] = b1[i] + alpha[0] * W1[(size_t)D_IN * H_DIM + i];
}

// ---------------- prep: gwa4[d] = ln_g[d]*Wa[d][0..3]; S1,S2 consts --------
__global__ __launch_bounds__(512) void prep_gwa(const float* __restrict__ ln_g,
                                                const float* __restrict__ ln_b,
                                                const float* __restrict__ Wa,
                                                f32x4* __restrict__ gwa4,
                                                float* __restrict__ consts) {
  int d = threadIdx.x;
  if (d < 8) consts[d] = 0.f;
  __syncthreads();
  float gg = ln_g[d], bb = ln_b[d];
  f32x4 wa = *(const f32x4*)(Wa + (size_t)d * 4);
  f32x4 gw;
  gw[0] = gg * wa[0]; gw[1] = gg * wa[1]; gw[2] = gg * wa[2]; gw[3] = gg * wa[3];
  gwa4[d] = gw;
  atomicAdd(&consts[0], gw[0]); atomicAdd(&consts[1], gw[1]);
  atomicAdd(&consts[2], gw[2]); atomicAdd(&consts[3], gw[3]);
  atomicAdd(&consts[4], bb * wa[0]); atomicAdd(&consts[5], bb * wa[1]);
  atomicAdd(&consts[6], bb * wa[2]); atomicAdd(&consts[7], bb * wa[3]);
}

// ---------------- cast x (fp32) -> xb (bf16) -------------------------------
__global__ void cast_x_kernel(const float* __restrict__ x, u16* __restrict__ xb, long n4) {
  long i = (long)blockIdx.x * 256 + threadIdx.x;
  if (i >= n4) return;
  f32x4 v = *(const f32x4*)(x + i * 4);
  u16x4 o;
  o[0] = f2bf(v[0]); o[1] = f2bf(v[1]); o[2] = f2bf(v[2]); o[3] = f2bf(v[3]);
  *(u16x4*)(xb + i * 4) = o;
}

// ---------------- transpose + cast: in[R][C] fp32 -> out[C][R] bf16 --------
__global__ __launch_bounds__(256) void transpose_cast(const float* __restrict__ in,
                                                      u16* __restrict__ outT,
                                                      int R, int Cc) {
  __shared__ float t[32][33];
  const int c0 = blockIdx.x * 32, r0 = blockIdx.y * 32;
  const int tx = threadIdx.x, ty = threadIdx.y;  // 32 x 8
#pragma unroll
  for (int i = 0; i < 4; ++i)
    t[ty + 8 * i][tx] = in[(size_t)(r0 + ty + 8 * i) * Cc + c0 + tx];
  __syncthreads();
#pragma unroll
  for (int i = 0; i < 4; ++i) {
    int oc = ty + 8 * i;
    outT[(size_t)(c0 + oc) * R + r0 + tx] = f2bf(t[tx][oc]);
  }
}

// ============================================================================
// NT GEMM — r19 FINAL (best: 660 us total). 128x128 tile, BK=64, 4 waves
// (2x2), 32 KiB LDS, global_load_lds DMA, 2-__syncthreads K-step, (256,3),
// VGPR 64, 0 bank conflicts, 16x16x32 MFMA.
// FUSE_LN=1 (GEMM2): epilogue computes the 6 LN-decomposed per-row sums;
// h2 never materialized; plain-store partial reduction (r18 atomic lesson).
// CLOSED LEVERS (r4-r20, measured): occupancy (VGPR 256-split: (256,5)/
// (512,8) spill), reg-staging (1.7x worse, m151), fp32-A staging (+47%),
// deep pipelines (5 variants 27-29%, 2 races), fused MLP (L2-BW-bound),
// atomic LN reduction (150MB RMW), 32x32 MFMA (4-way LDS conflict: 32 rows
// x 8 chunk positions -> 2.56e7 conflicts, +58% GEMM1 time).
// ============================================================================
template <int RELU, int FUSE_LN>
__global__ __launch_bounds__(256, 3) void gemm128h(const u16* __restrict__ A,
                                                   const u16* __restrict__ Bt,
                                                   const float* __restrict__ bias,
                                                   u16* __restrict__ C,
                                                   const f32x4* __restrict__ gwa4,
                                                   float* __restrict__ red,
                                                   size_t ctStride,
                                                   int M, int Nc, int K, int NTN) {
  __shared__ __align__(16) char smem[32768];
  const int tid = threadIdx.x;
  const int w = tid >> 6, l = tid & 63;
  const int wm = w >> 1, wn = w & 1;  // 2 x 2 waves
  const int lr = l & 15, g = l >> 4;

  // T1: bijective XCD swizzle (m204)
  const int nwg = gridDim.x;
  const int orig = blockIdx.x;
  const int qq = nwg >> 3, rr = nwg & 7, xcd = orig & 7, idx = orig >> 3;
  const int wgid = (xcd < rr ? xcd * (qq + 1) : rr * (qq + 1) + (xcd - rr) * qq) + idx;
  const int rowBase = (wgid / NTN) * 128;
  const int ct = wgid % NTN;
  const int colBase = ct * 128;

  const int NT = K >> 6;  // BK = 64

  // staging source pre-swizzle: LDS byte q holds global elem
  // o = q ^ (((q>>7)&7)<<4)
  int s_row[4], s_kel[4];
#pragma unroll
  for (int p = 0; p < 4; ++p) {
    int q = p * 4096 + w * 1024 + l * 16;
    int o = q ^ (((q >> 7) & 7) << 4);
    s_row[p] = o >> 7;          // row in [0,128)
    s_kel[p] = (o & 127) >> 1;  // k elem in [0,64)
  }

  f32x4 acc[4][4] = {};

  const int aRow = (wm * 64 + lr) * 128;
  const int bRow = (wn * 64 + lr) * 128;
  int ck[2];
  ck[0] = (g ^ (lr & 7)) << 4;
  ck[1] = ((4 + g) ^ (lr & 7)) << 4;

  for (int t = 0; t < NT; ++t) {
    __syncthreads();  // WAR
#pragma unroll
    for (int p = 0; p < 4; ++p) {
      int r = rowBase + s_row[p];
      if (r >= M) r = M - 1;
      const u16* asrc = A + (size_t)r * K + t * 64 + s_kel[p];
      __builtin_amdgcn_global_load_lds(
          (const __attribute__((address_space(1))) void*)asrc,
          (__attribute__((address_space(3))) void*)(smem + p * 4096 + w * 1024), 16, 0, 0);
    }
#pragma unroll
    for (int p = 0; p < 4; ++p) {
      int rc = colBase + s_row[p];
      const u16* bsrc = Bt + (size_t)rc * K + t * 64 + s_kel[p];
      __builtin_amdgcn_global_load_lds(
          (const __attribute__((address_space(1))) void*)bsrc,
          (__attribute__((address_space(3))) void*)(smem + 16384 + p * 4096 + w * 1024), 16, 0, 0);
    }
    __syncthreads();  // publish

#pragma unroll
    for (int kk = 0; kk < 2; ++kk) {
      bf16x8 af[4], bf[4];
#pragma unroll
      for (int mi = 0; mi < 4; ++mi)
        af[mi] = *(const bf16x8*)(smem + aRow + mi * 2048 + ck[kk]);
#pragma unroll
      for (int ni = 0; ni < 4; ++ni)
        bf[ni] = *(const bf16x8*)(smem + 16384 + bRow + ni * 2048 + ck[kk]);
      __builtin_amdgcn_s_setprio(1);
#pragma unroll
      for (int mi = 0; mi < 4; ++mi)
#pragma unroll
        for (int ni = 0; ni < 4; ++ni)
          acc[mi][ni] = __builtin_amdgcn_mfma_f32_16x16x32_bf16(af[mi], bf[ni], acc[mi][ni], 0, 0, 0);
      __builtin_amdgcn_s_setprio(0);
    }
  }

  if (FUSE_LN) {
    float* redc = red + (size_t)ct * ctStride;
#pragma unroll
    for (int mi = 0; mi < 4; ++mi) {
      float dt[4][4], sv[4], sq[4];
#pragma unroll
      for (int r = 0; r < 4; ++r) {
        sv[r] = 0.f; sq[r] = 0.f;
#pragma unroll
        for (int h = 0; h < 4; ++h) dt[r][h] = 0.f;
      }
#pragma unroll
      for (int ni = 0; ni < 4; ++ni) {
        int col = colBase + wn * 64 + ni * 16 + lr;
        f32x4 gw = gwa4[col];
        float bb = bias[col];
#pragma unroll
        for (int r = 0; r < 4; ++r) {
          float v = acc[mi][ni][r] + bb;
          if (RELU) v = fmaxf(v, 0.f);
          sv[r] += v; sq[r] += v * v;
          dt[r][0] += v * gw[0]; dt[r][1] += v * gw[1];
          dt[r][2] += v * gw[2]; dt[r][3] += v * gw[3];
        }
      }
#pragma unroll
      for (int off = 1; off < 16; off <<= 1) {
#pragma unroll
        for (int r = 0; r < 4; ++r) {
          sv[r] += __shfl_xor(sv[r], off);
          sq[r] += __shfl_xor(sq[r], off);
#pragma unroll
          for (int h = 0; h < 4; ++h) dt[r][h] += __shfl_xor(dt[r][h], off);
        }
      }
      if (lr == 0) {
#pragma unroll
        for (int r = 0; r < 4; ++r) {
          int row = rowBase + wm * 64 + mi * 16 + g * 4 + r;
          if (row < M) {
            float* rp = redc + ((size_t)row * 2 + wn) * 6;
            rp[0] = dt[r][0]; rp[1] = dt[r][1]; rp[2] = dt[r][2];
            rp[3] = dt[r][3]; rp[4] = sv[r];    rp[5] = sq[r];
          }
        }
      }
    }
  } else {
    float bv[4];
#pragma unroll
    for (int ni = 0; ni < 4; ++ni) bv[ni] = bias[colBase + wn * 64 + ni * 16 + lr];
#pragma unroll
    for (int mi = 0; mi < 4; ++mi) {
#pragma unroll
      for (int r = 0; r < 4; ++r) {
        int row = rowBase + wm * 64 + mi * 16 + g * 4 + r;
        if (row < M) {
#pragma unroll
          for (int ni = 0; ni < 4; ++ni) {
            float v = acc[mi][ni][r] + bv[ni];
            if (RELU) v = fmaxf(v, 0.f);
            C[(size_t)row * Nc + colBase + wn * 64 + ni * 16 + lr] = f2bf(v);
          }
        }
      }
    }
  }
}

// ---------------- finalize LN + att + sigmoid + exp + seg-sum --------------
// sums 8 partials (4 col-tiles x 2 wn-halves), then
// raw[h] = rstd*(dot_h - mu*S1[h]) + S2[h] + ba[h]; segmax skipped (sigmoid
// in (0,1) => exp bounded by e, cancels in e/sum — verified r14-r19).
__global__ void ln_final(const float* __restrict__ red, size_t ctStride,
                         const float* __restrict__ consts,
                         const float* __restrict__ ba, const int* __restrict__ row,
                         float* __restrict__ att, float* __restrict__ segsum) {
  int n = blockIdx.x * 256 + threadIdx.x;
  if (n >= N_ROWS) return;
  float acc6[6] = {0.f, 0.f, 0.f, 0.f, 0.f, 0.f};
#pragma unroll
  for (int ct = 0; ct < 4; ++ct) {
#pragma unroll
    for (int hw = 0; hw < 2; ++hw) {
      const float* rp = red + (size_t)ct * ctStride + ((size_t)n * 2 + hw) * 6;
#pragma unroll
      for (int k = 0; k < 6; ++k) acc6[k] += rp[k];
    }
  }
  float mu = acc6[4] * (1.f / 512.f);
  float var = acc6[5] * (1.f / 512.f) - mu * mu;
  float rstd = rsqrtf(var + 1e-5f);
  int rid = row[n];
#pragma unroll
  for (int h = 0; h < 4; ++h) {
    float raw = rstd * (acc6[h] - mu * consts[h]) + consts[4 + h] + ba[h];
    float sg = 1.f / (1.f + expf(-raw));
    float e = expf(sg);
    att[(size_t)n * 4 + h] = e;
    atomicAdd(&segsum[(size_t)rid * 4 + h], e);
  }
}

// ---------------- normalize + head-mean ------------------------------------
__global__ void seg_norm(const float* __restrict__ att, const int* __restrict__ row,
                         const float* __restrict__ segsum, float* __restrict__ out) {
  int n = blockIdx.x * 256 + threadIdx.x;
  if (n >= N_ROWS) return;
  int rid = row[n];
  float s = 0.f;
#pragma unroll
  for (int h = 0; h < 4; ++h)
    s += att[(size_t)n * 4 + h] / segsum[(size_t)rid * 4 + h];
  out[n] = 0.25f * s;
}

extern "C" void kernel_launch(void* const* d_in, const int* in_sizes, int n_in,
                              void* d_out, int out_size, void* d_ws, size_t ws_size,
                              hipStream_t stream) {
  const float* x = (const float*)d_in[0];
  const int* row = (const int*)d_in[1];
  const float* alpha = (const float*)d_in[2];
  const float* W1 = (const float*)d_in[3];
  const float* b1 = (const float*)d_in[4];
  const float* W2 = (const float*)d_in[5];
  const float* b2 = (const float*)d_in[6];
  const float* ln_g = (const float*)d_in[7];
  const float* ln_b = (const float*)d_in[8];
  const float* Wa = (const float*)d_in[9];
  const float* ba = (const float*)d_in[10];
  float* out = (float*)d_out;

  char* ws = (char*)d_ws;
  size_t off = 0;
  auto alloc = [&](size_t bytes) {
    void* p = ws + off;
    off += (bytes + 255) & ~(size_t)255;
    return p;
  };
  // fixed buffers
  u16* W1t = (u16*)alloc((size_t)H_DIM * D_IN * 2);
  u16* W2t = (u16*)alloc((size_t)D_IN * H_DIM * 2);
  float* bias1 = (float*)alloc(H_DIM * 4);
  float* att = (float*)alloc((size_t)N_ROWS * HEADS * 4);
  float* segsum = (float*)alloc(NSEG * HEADS * 4);
  f32x4* gwa4 = (f32x4*)alloc(D_IN * 16);
  float* consts = (float*)alloc(8 * 4);
  // red: [4 ct][N_ROWS][2 wn][6] floats = 19.2 MB, plain stores only
  const size_t ctStride = (size_t)N_ROWS * 2 * 6;
  float* red = (float*)alloc(4 * ctStride * 4);

  // slab sizing from remaining ws: per-row 5120 B (xb 1KB + h1 4KB)
  const size_t per_row = ((size_t)D_IN + H_DIM) * 2;
  const size_t reserve = (size_t)1 << 20;
  size_t usable = (ws_size > off + reserve) ? (ws_size - off - reserve) : 0;
  long slab_l = (long)(usable / per_row);
  const int maxslab = (N_ROWS + 127) & ~127;  // 100096
  int slab;
  if (slab_l >= maxslab) slab = maxslab;
  else slab = (int)(slab_l & ~127L);
  if (slab < 128) slab = 128;

  u16* xb = (u16*)alloc((size_t)slab * D_IN * 2);
  u16* h1 = (u16*)alloc((size_t)slab * H_DIM * 2);

  init_misc<<<(NSEG * HEADS + 255) / 256, 256, 0, stream>>>(W1, b1, alpha, bias1, segsum);
  prep_gwa<<<1, 512, 0, stream>>>(ln_g, ln_b, Wa, gwa4, consts);
  transpose_cast<<<dim3(H_DIM / 32, D_IN / 32), dim3(32, 8), 0, stream>>>(W1, W1t, D_IN, H_DIM);
  transpose_cast<<<dim3(D_IN / 32, H_DIM / 32), dim3(32, 8), 0, stream>>>(W2, W2t, H_DIM, D_IN);

  for (int s0 = 0; s0 < N_ROWS; s0 += slab) {
    int rows = N_ROWS - s0 < slab ? N_ROWS - s0 : slab;
    int ntm = (rows + 127) / 128;
    long n4 = (long)rows * D_IN / 4;
    cast_x_kernel<<<(int)((n4 + 255) / 256), 256, 0, stream>>>(x + (size_t)s0 * D_IN, xb, n4);
    gemm128h<1, 0><<<ntm * (H_DIM / 128), 256, 0, stream>>>(
        xb, W1t, bias1, h1, nullptr, nullptr, 0, rows, H_DIM, D_IN, H_DIM / 128);
    gemm128h<1, 1><<<ntm * (D_IN / 128), 256, 0, stream>>>(
        h1, W2t, b2, nullptr, gwa4, red + (size_t)s0 * 2 * 6, ctStride,
        rows, D_IN, H_DIM, D_IN / 128);
  }

  ln_final<<<(N_ROWS + 255) / 256, 256, 0, stream>>>(red, ctStride, consts, ba, row, att, segsum);
  seg_norm<<<(N_ROWS + 255) / 256, 256, 0, stream>>>(att, row, segsum, out);
}